// Round 1
// baseline (390.452 us; speedup 1.0000x reference)
//
#include <hip/hip_runtime.h>

typedef short short8 __attribute__((ext_vector_type(8)));
typedef float floatx16 __attribute__((ext_vector_type(16)));
typedef float floatx4 __attribute__((ext_vector_type(4)));
typedef unsigned int uint4v __attribute__((ext_vector_type(4)));

#define ROWS 81
#define CDIM 256
#define XOFF 0
#define QOFF 41472              // 81*512
#define SOFF 62208              // QOFF + 81*256
#define AOFF 63232              // SOFF + 16*16*4
#define SMEM_TOTAL 63616        // AOFF + 81*4 (padded)

__device__ __forceinline__ unsigned short f2bf(float f) {
    union { float f; unsigned int u; } v; v.f = f;
    return (unsigned short)((v.u + 0x7FFFu + ((v.u >> 16) & 1u)) >> 16);
}

__global__ void wconv_kernel(const float* __restrict__ W,
                             unsigned short* __restrict__ Wb, int n) {
    int i = blockIdx.x * 256 + threadIdx.x;
    if (i < n) Wb[i] = f2bf(W[i]);
}

__global__ __launch_bounds__(256, 2)
void attn_kernel(const float* __restrict__ x,
                 const unsigned short* __restrict__ Wb,
                 const float* __restrict__ b_fc,
                 const int* __restrict__ block_idx,
                 const int* __restrict__ match_vec,
                 float* __restrict__ out)
{
    __shared__ __align__(16) char smem[SMEM_TOTAL];
    const int b    = blockIdx.x;
    const int t    = threadIdx.x;
    const int lane = t & 63;
    const int wave = t >> 6;
    const int lrow = lane & 31;
    const int khalf = lane >> 5;

    // prefetch the mask flag early (hides dependent-load latency)
    int cur_match = 0;
    if (t < 9) cur_match = match_vec[block_idx[b]];

    // ---- preload this wave's 16 W^T B-fragments (L2-hot) ----
    short8 bfrag[16];
    {
        const unsigned short* wr = Wb + (wave * 32 + lrow) * CDIM;
#pragma unroll
        for (int ks = 0; ks < 16; ++ks)
            bfrag[ks] = *(const short8*)(wr + ks * 16 + khalf * 8);
    }
    const float bias = b_fc[wave * 32 + lrow];

    // ---- stage x -> LDS bf16, patch-major rows, XOR-swizzled ----
    {
        const float* xb = x + (long)b * (ROWS * CDIM);
        for (int k = t; k < ROWS * 32; k += 256) {
            int gr = k >> 5;                 // (h,w) source row
            int c0 = (k & 31) * 8;
            float4 a0 = *(const float4*)(xb + gr * CDIM + c0);
            float4 a1 = *(const float4*)(xb + gr * CDIM + c0 + 4);
            int hh = gr / 9, ww = gr % 9;
            int r = ((hh / 3) * 3 + (ww / 3)) * 9 + ((hh % 3) * 3 + (ww % 3));
            short8 v;
            v[0] = (short)f2bf(a0.x); v[1] = (short)f2bf(a0.y);
            v[2] = (short)f2bf(a0.z); v[3] = (short)f2bf(a0.w);
            v[4] = (short)f2bf(a1.x); v[5] = (short)f2bf(a1.y);
            v[6] = (short)f2bf(a1.z); v[7] = (short)f2bf(a1.w);
            int off = r * 512 + ((c0 * 2) ^ ((r & 15) << 4));
            *(short8*)(smem + off) = v;
        }
    }
    __syncthreads();

    // ---- q[96x128] = x[96x256] @ W^T via 32x32x16 bf16 MFMA ----
    floatx16 acc0, acc1, acc2;
#pragma unroll
    for (int i = 0; i < 16; ++i) { acc0[i] = 0.f; acc1[i] = 0.f; acc2[i] = 0.f; }
    const int sw = (lrow & 15) << 4;
#pragma unroll
    for (int ks = 0; ks < 16; ++ks) {
        int cb = (ks * 32 + khalf * 16) ^ sw;
        short8 a0 = *(const short8*)(smem + (lrow      ) * 512 + cb);
        short8 a1 = *(const short8*)(smem + (lrow + 32 ) * 512 + cb);
        short8 a2 = *(const short8*)(smem + (lrow + 64 ) * 512 + cb);
        acc0 = __builtin_amdgcn_mfma_f32_32x32x16_bf16(a0, bfrag[ks], acc0, 0, 0, 0);
        acc1 = __builtin_amdgcn_mfma_f32_32x32x16_bf16(a1, bfrag[ks], acc1, 0, 0, 0);
        acc2 = __builtin_amdgcn_mfma_f32_32x32x16_bf16(a2, bfrag[ks], acc2, 0, 0, 0);
    }

    // ---- bias + store q to LDS as bf16 (swizzled) ----
    {
        int hcol2 = (wave * 32 + lrow) * 2;
#pragma unroll
        for (int reg = 0; reg < 16; ++reg) {
            int rb = (reg & 3) + 8 * (reg >> 2) + 4 * khalf;
            int r0 = rb, r1 = rb + 32, r2 = rb + 64;
            *(unsigned short*)(smem + QOFF + r0 * 256 + (hcol2 ^ ((r0 & 15) << 4))) = f2bf(acc0[reg] + bias);
            *(unsigned short*)(smem + QOFF + r1 * 256 + (hcol2 ^ ((r1 & 15) << 4))) = f2bf(acc1[reg] + bias);
            if (r2 < ROWS)
                *(unsigned short*)(smem + QOFF + r2 * 256 + (hcol2 ^ ((r2 & 15) << 4))) = f2bf(acc2[reg] + bias);
        }
    }
    __syncthreads();

    // ---- scores = q_flat @ q_flat^T  (wave 0; A-frag == B-frag) ----
    if (wave == 0) {
        floatx4 sacc;
#pragma unroll
        for (int i = 0; i < 4; ++i) sacc[i] = 0.f;
        int n  = lane & 15;
        int nc = (n < 9) ? n : 8;            // clamp: rows/cols >=9 discarded
        int kg = lane >> 4;
#pragma unroll
        for (int ks = 0; ks < 36; ++ks) {
            int k  = ks * 32 + kg * 8;
            int p  = k >> 7;
            int h0 = (k & 127) * 2;
            int row = nc * 9 + p;
            short8 f = *(const short8*)(smem + QOFF + row * 256 + (h0 ^ ((row & 15) << 4)));
            sacc = __builtin_amdgcn_mfma_f32_16x16x32_bf16(f, f, sacc, 0, 0, 0);
        }
        float* sc = (float*)(smem + SOFF);
#pragma unroll
        for (int reg = 0; reg < 4; ++reg)
            sc[(kg * 4 + reg) * 16 + n] = sacc[reg];
    }
    __syncthreads();

    // ---- masked softmax, rows 0..8 by threads 0..8 ----
    if (t < 9) {
        const float scale = 0.029462782549439483f;   // (128*9)^-0.5
        float* sc = (float*)(smem + SOFF);
        float* at = (float*)(smem + AOFF);
        float s[9];
        float mx = -1e30f;
#pragma unroll
        for (int m = 0; m < 9; ++m) {
            float v = sc[t * 16 + m] * scale;
            if (m == t && cur_match != 1) v -= 100.f;
            s[m] = v;
            mx = fmaxf(mx, v);
        }
        float sum = 0.f;
#pragma unroll
        for (int m = 0; m < 9; ++m) { s[m] = __expf(s[m] - mx); sum += s[m]; }
        float inv = 1.f / sum;
#pragma unroll
        for (int m = 0; m < 9; ++m) at[t * 9 + m] = s[m] * inv;
    }
    __syncthreads();

    // ---- out = attn @ v (f32 VALU, bf16 v from LDS), permuted store ----
    {
        const float* at = (const float*)(smem + AOFF);
        float* ob = out + (long)b * (ROWS * CDIM);
        for (int k = t; k < ROWS * 32; k += 256) {
            int r  = k >> 5;
            int c0 = (k & 31) * 8;
            int n = r / 9, p = r % 9;
            float o[8];
#pragma unroll
            for (int i = 0; i < 8; ++i) o[i] = 0.f;
#pragma unroll
            for (int m = 0; m < 9; ++m) {
                float a = at[n * 9 + m];
                int row = m * 9 + p;
                uint4v u = *(const uint4v*)(smem + row * 512 + ((c0 * 2) ^ ((row & 15) << 4)));
                o[0] += a * __uint_as_float(u.x << 16);
                o[1] += a * __uint_as_float(u.x & 0xffff0000u);
                o[2] += a * __uint_as_float(u.y << 16);
                o[3] += a * __uint_as_float(u.y & 0xffff0000u);
                o[4] += a * __uint_as_float(u.z << 16);
                o[5] += a * __uint_as_float(u.z & 0xffff0000u);
                o[6] += a * __uint_as_float(u.w << 16);
                o[7] += a * __uint_as_float(u.w & 0xffff0000u);
            }
            int hh = (n / 3) * 3 + (p / 3);
            int ww = (n % 3) * 3 + (p % 3);
            int gr = hh * 9 + ww;
            *(float4*)(ob + gr * CDIM + c0)     = make_float4(o[0], o[1], o[2], o[3]);
            *(float4*)(ob + gr * CDIM + c0 + 4) = make_float4(o[4], o[5], o[6], o[7]);
        }
    }
}

extern "C" void kernel_launch(void* const* d_in, const int* in_sizes, int n_in,
                              void* d_out, int out_size, void* d_ws, size_t ws_size,
                              hipStream_t stream) {
    const float* x    = (const float*)d_in[0];
    const float* W    = (const float*)d_in[1];
    const float* bfc  = (const float*)d_in[2];
    const int*   bidx = (const int*)d_in[3];
    const int*   mvec = (const int*)d_in[4];
    float* outp = (float*)d_out;
    unsigned short* Wb = (unsigned short*)d_ws;

    int nW = in_sizes[1];                       // 128*256
    wconv_kernel<<<(nW + 255) / 256, 256, 0, stream>>>(W, Wb, nW);

    int B = in_sizes[0] / (ROWS * CDIM);        // 8192
    attn_kernel<<<B, 256, 0, stream>>>(x, Wb, bfc, bidx, mvec, outp);
}

// Round 2
// 371.432 us; speedup vs baseline: 1.0512x; 1.0512x over previous
//
#include <hip/hip_runtime.h>

typedef short short8 __attribute__((ext_vector_type(8)));
typedef float floatx16 __attribute__((ext_vector_type(16)));
typedef float floatx4 __attribute__((ext_vector_type(4)));
typedef unsigned int uint4v __attribute__((ext_vector_type(4)));

#define ROWS 81
#define CDIM 256
#define QOFF 41472              // 81*512  (x tile, bf16, swizzled)
#define SOFF 62208              // QOFF + 81*256 (q tile, bf16, swizzled)
#define ABOFF 63232             // SOFF + 16*16*4 (scores f32)
#define SMEM_TOTAL 63744        // ABOFF + 16*32 (attn bf16, 16 rows x 16 ushort)

__device__ __forceinline__ unsigned short f2bf(float f) {
    union { float f; unsigned int u; } v; v.f = f;
    return (unsigned short)((v.u + 0x7FFFu + ((v.u >> 16) & 1u)) >> 16);
}

__global__ void wconv_kernel(const float* __restrict__ W,
                             unsigned short* __restrict__ Wb, int n) {
    int i = blockIdx.x * 256 + threadIdx.x;
    if (i < n) Wb[i] = f2bf(W[i]);
}

__global__ __launch_bounds__(512, 4)
void attn_kernel(const float* __restrict__ x,
                 const unsigned short* __restrict__ Wb,
                 const float* __restrict__ b_fc,
                 const int* __restrict__ block_idx,
                 const int* __restrict__ match_vec,
                 float* __restrict__ out)
{
    __shared__ __align__(16) char smem[SMEM_TOTAL];
    const int b     = blockIdx.x;
    const int t     = threadIdx.x;
    const int lane  = t & 63;
    const int wave  = t >> 6;       // 0..7
    const int l15   = lane & 15;
    const int kg    = lane >> 4;    // 0..3
    const int l31   = lane & 31;
    const int khalf = lane >> 5;    // 0..1

    int cur_match = 0;
    if (t < 9) cur_match = match_vec[block_idx[b]];

    // ---- preload this wave's W^T B-fragments (16 h-cols per wave, L2-hot) ----
    short8 wfrag[8];
    {
        const unsigned short* wr = Wb + (wave * 16 + l15) * CDIM + kg * 8;
#pragma unroll
        for (int ks = 0; ks < 8; ++ks)
            wfrag[ks] = *(const short8*)(wr + ks * 32);
    }
    const float bias = b_fc[wave * 16 + l15];

    // ---- stage x -> LDS bf16, patch-major rows, XOR-swizzled ----
    {
        const float* xb = x + (long)b * (ROWS * CDIM);
        for (int k = t; k < ROWS * 32; k += 512) {
            int gr = k >> 5;                 // (h,w) source row
            int c0 = (k & 31) * 8;
            float4 a0 = *(const float4*)(xb + gr * CDIM + c0);
            float4 a1 = *(const float4*)(xb + gr * CDIM + c0 + 4);
            int hh = gr / 9, ww = gr % 9;
            int r = ((hh / 3) * 3 + (ww / 3)) * 9 + ((hh % 3) * 3 + (ww % 3));
            short8 v;
            v[0] = (short)f2bf(a0.x); v[1] = (short)f2bf(a0.y);
            v[2] = (short)f2bf(a0.z); v[3] = (short)f2bf(a0.w);
            v[4] = (short)f2bf(a1.x); v[5] = (short)f2bf(a1.y);
            v[6] = (short)f2bf(a1.z); v[7] = (short)f2bf(a1.w);
            int off = r * 512 + ((c0 * 2) ^ ((r & 15) << 4));
            *(short8*)(smem + off) = v;
        }
    }
    __syncthreads();

    // ---- q[96x128] = x[96x256] @ W^T via 16x16x32: 6 row-tiles x 8 ksteps ----
    floatx4 acc[6];
#pragma unroll
    for (int i = 0; i < 6; ++i)
#pragma unroll
        for (int j = 0; j < 4; ++j) acc[i][j] = 0.f;
    const int swl = l15 << 4;
#pragma unroll
    for (int ks = 0; ks < 8; ++ks) {
        int cb = ks * 64 + kg * 16;          // byte offset of k within row
#pragma unroll
        for (int tile = 0; tile < 6; ++tile) {
            int r = tile * 16 + l15;
            short8 a = *(const short8*)(smem + r * 512 + (cb ^ swl));
            acc[tile] = __builtin_amdgcn_mfma_f32_16x16x32_bf16(a, wfrag[ks], acc[tile], 0, 0, 0);
        }
    }

    // ---- bias + store q to LDS bf16 (swizzled) ----
    {
        int h2 = (wave * 16 + l15) * 2;      // byte col of h
#pragma unroll
        for (int tile = 0; tile < 6; ++tile) {
#pragma unroll
            for (int reg = 0; reg < 4; ++reg) {
                int r = tile * 16 + kg * 4 + reg;
                if (r < ROWS)
                    *(unsigned short*)(smem + QOFF + r * 256 + (h2 ^ ((r & 15) << 4))) =
                        f2bf(acc[tile][reg] + bias);
            }
        }
    }
    __syncthreads();

    // ---- scores = q_flat @ q_flat^T (wave 0, 4 interleaved acc chains) ----
    if (wave == 0) {
        floatx4 s0, s1, s2, s3;
#pragma unroll
        for (int i = 0; i < 4; ++i) { s0[i] = 0.f; s1[i] = 0.f; s2[i] = 0.f; s3[i] = 0.f; }
        int nc = (l15 < 9) ? l15 : 8;
#pragma unroll
        for (int s = 0; s < 9; ++s) {
#pragma unroll
            for (int i = 0; i < 4; ++i) {
                int ks = i * 9 + s;
                int k  = ks * 32 + kg * 8;
                int p  = k >> 7;
                int h0 = (k & 127) * 2;
                int row = nc * 9 + p;
                short8 f = *(const short8*)(smem + QOFF + row * 256 + (h0 ^ ((row & 15) << 4)));
                floatx4 tmp = __builtin_amdgcn_mfma_f32_16x16x32_bf16(f, f, (i==0?s0:i==1?s1:i==2?s2:s3), 0, 0, 0);
                if (i == 0) s0 = tmp; else if (i == 1) s1 = tmp; else if (i == 2) s2 = tmp; else s3 = tmp;
            }
        }
        float* sc = (float*)(smem + SOFF);
#pragma unroll
        for (int reg = 0; reg < 4; ++reg)
            sc[(kg * 4 + reg) * 16 + l15] = s0[reg] + s1[reg] + s2[reg] + s3[reg];
    }
    __syncthreads();

    // ---- masked softmax rows 0..8; write attn as bf16 [16][16] zero-padded ----
    if (t < 9) {
        const float scale = 0.029462782549439483f;   // (128*9)^-0.5
        float* sc = (float*)(smem + SOFF);
        float s[9];
        float mx = -1e30f;
#pragma unroll
        for (int m = 0; m < 9; ++m) {
            float v = sc[t * 16 + m] * scale;
            if (m == t && cur_match != 1) v -= 100.f;
            s[m] = v;
            mx = fmaxf(mx, v);
        }
        float sum = 0.f;
#pragma unroll
        for (int m = 0; m < 9; ++m) { s[m] = __expf(s[m] - mx); sum += s[m]; }
        float inv = 1.f / sum;
        unsigned short* ab = (unsigned short*)(smem + ABOFF) + t * 16;
#pragma unroll
        for (int m = 0; m < 9; ++m) ab[m] = f2bf(s[m] * inv);
#pragma unroll
        for (int m = 9; m < 16; ++m) ab[m] = 0;
    }
    __syncthreads();

    // ---- out^T = v^T @ attn^T via 32x32x16 MFMA; 9 d-tiles per wave ----
    {
        const int n  = l31;                   // token (output row), valid < 9
        const int nm = (n < 9) ? n : 0;
        short8 bf = *(const short8*)(smem + ABOFF + nm * 32 + khalf * 16);
        float* ob = out + (long)b * (ROWS * CDIM);
        int hh = 0, ww = 0;
        if (n < 9) { hh = (n / 3) * 3; ww = (n % 3) * 3; }
#pragma unroll
        for (int tt = 0; tt < 9; ++tt) {
            int tile = wave * 9 + tt;
            int d = tile * 32 + l31;
            int p = d >> 8, c = d & 255;
            short8 af;
#pragma unroll
            for (int j = 0; j < 8; ++j) {
                int m = khalf * 8 + j; if (m > 8) m = 8;   // m>8: B is zero
                int row = m * 9 + p;
                af[j] = *(const short*)(smem + row * 512 + ((c * 2) ^ ((row & 15) << 4)));
            }
            floatx16 dacc;
#pragma unroll
            for (int i = 0; i < 16; ++i) dacc[i] = 0.f;
            dacc = __builtin_amdgcn_mfma_f32_32x32x16_bf16(af, bf, dacc, 0, 0, 0);
            if (n < 9) {
#pragma unroll
                for (int q2 = 0; q2 < 4; ++q2) {
                    int d0 = tile * 32 + q2 * 8 + khalf * 4;
                    int p0 = d0 >> 8, c0 = d0 & 255;
                    int gr = (hh + (p0 / 3)) * 9 + (ww + (p0 % 3));
                    *(float4*)(ob + gr * CDIM + c0) =
                        make_float4(dacc[q2 * 4 + 0], dacc[q2 * 4 + 1],
                                    dacc[q2 * 4 + 2], dacc[q2 * 4 + 3]);
                }
            }
        }
    }
}

extern "C" void kernel_launch(void* const* d_in, const int* in_sizes, int n_in,
                              void* d_out, int out_size, void* d_ws, size_t ws_size,
                              hipStream_t stream) {
    const float* x    = (const float*)d_in[0];
    const float* W    = (const float*)d_in[1];
    const float* bfc  = (const float*)d_in[2];
    const int*   bidx = (const int*)d_in[3];
    const int*   mvec = (const int*)d_in[4];
    float* outp = (float*)d_out;
    unsigned short* Wb = (unsigned short*)d_ws;

    int nW = in_sizes[1];                       // 128*256
    wconv_kernel<<<(nW + 255) / 256, 256, 0, stream>>>(W, Wb, nW);

    int B = in_sizes[0] / (ROWS * CDIM);        // 8192
    attn_kernel<<<B, 512, 0, stream>>>(x, Wb, bfc, bidx, mvec, outp);
}